// Round 18
// baseline (142.392 us; speedup 1.0000x reference)
//
#include <hip/hip_runtime.h>

typedef unsigned short u16;
typedef __attribute__((ext_vector_type(8))) short bf16x8;
typedef __attribute__((ext_vector_type(4))) float f32x4;
typedef __attribute__((ext_vector_type(4))) unsigned short us4;

#define B_ 2
#define S_ 2048
#define D_ 1024
#define H_ 16
#define DH_ 64
#define M_ 4096 /* B*S */

__device__ __forceinline__ u16 f2bf(float f) {
  unsigned int u = __builtin_bit_cast(unsigned int, f);
  u += 0x7FFFu + ((u >> 16) & 1u);   // RNE
  return (u16)(u >> 16);
}

__device__ __forceinline__ unsigned int cvtpk(float lo, float hi) {
  unsigned int r;
  asm("v_cvt_pk_bf16_f32 %0, %1, %2" : "=v"(r) : "v"(lo), "v"(hi));
  return r;
}

__device__ __forceinline__ float fexp2(float x) {  // v_exp_f32 IS exp2
  float r;
  asm("v_exp_f32 %0, %1" : "=v"(r) : "v"(x));
  return r;
}

__device__ __forceinline__ void gload_lds16(const void* g, void* l) {
  __builtin_amdgcn_global_load_lds(
      (__attribute__((address_space(1))) void*)(g),
      (__attribute__((address_space(3))) void*)(l),
      16, 0, 0);
}

// ---------------- prep: z<4 -> W[z] transpose+cvt; z>=4 -> q/k/v fp32->bf16 ----------
__global__ __launch_bounds__(256) void wprep_kernel(const float* __restrict__ W0,
                                                    const float* __restrict__ W1,
                                                    const float* __restrict__ W2,
                                                    const float* __restrict__ W3,
                                                    u16* __restrict__ Wt,
                                                    const float* __restrict__ qin,
                                                    const float* __restrict__ kin,
                                                    const float* __restrict__ vin,
                                                    u16* __restrict__ Xq,
                                                    u16* __restrict__ Xk,
                                                    u16* __restrict__ Xv) {
  int z = blockIdx.z;
  if (z < 4) {
    __shared__ float tile[32][33];
    const float* W = (z == 0) ? W0 : (z == 1) ? W1 : (z == 2) ? W2 : W3;
    u16* out = Wt + (size_t)z * D_ * D_;
    int tx = threadIdx.x, ty = threadIdx.y;
    int x = blockIdx.x * 32 + tx;
    for (int j = 0; j < 32; j += 8)
      tile[ty + j][tx] = W[(size_t)(blockIdx.y * 32 + ty + j) * D_ + x];
    __syncthreads();
    int x2 = blockIdx.y * 32 + tx;
    for (int j = 0; j < 32; j += 8)
      out[(size_t)(blockIdx.x * 32 + ty + j) * D_ + x2] = f2bf(tile[tx][ty + j]);
  } else {
    int zz = z - 4;
    const float* src = (zz == 0) ? qin : (zz == 1) ? kin : vin;
    u16* dst = (zz == 0) ? Xq : (zz == 1) ? Xk : Xv;
    int bid = blockIdx.y * 32 + blockIdx.x;
    int t = threadIdx.y * 32 + threadIdx.x;
    const float4* s4 = (const float4*)src;
    for (int i = 0; i < 4; ++i) {
      int idx = bid * 1024 + i * 256 + t;
      float4 v4 = s4[idx];
      us4 o;
      o[0] = f2bf(v4.x); o[1] = f2bf(v4.y); o[2] = f2bf(v4.z); o[3] = f2bf(v4.w);
      ((us4*)dst)[idx] = o;
    }
  }
}

// ---------------- QKV GEMM: BK=64, XOR-swizzled LDS tiles (round-17 winner) ----------
__global__ __launch_bounds__(256) void gemm_qkv(const u16* __restrict__ Xq,
                                                const u16* __restrict__ Xk,
                                                const u16* __restrict__ Xv,
                                                const u16* __restrict__ Wt,
                                                const float* __restrict__ bq,
                                                const float* __restrict__ bk,
                                                const float* __restrict__ bv,
                                                u16* __restrict__ Qh,
                                                u16* __restrict__ Kh,
                                                u16* __restrict__ Vt) {
  __shared__ u16 As[128 * 64];   // 16 KB
  __shared__ u16 Bs[128 * 64];   // 16 KB
  int fid = blockIdx.x;
  int xcd = fid & 7, ii = fid >> 3;
  int grp = ii >> 3, yy = ii & 7;
  int gg = xcd * 12 + grp;
  int z = gg >> 5;
  int xx = gg & 31;
  const u16* A = (z == 0) ? Xq : (z == 1) ? Xk : Xv;
  const u16* Bt = Wt + (size_t)z * D_ * D_;
  const float* bias = (z == 0) ? bq : (z == 1) ? bk : bv;
  u16* O = (z == 0) ? Qh : (z == 1) ? Kh : Vt;

  int tid = threadIdx.x;
  int lane = tid & 63, wave = tid >> 6;
  int m0 = xx * 128, n0 = yy * 128;
  int wr = wave >> 1, wc = wave & 1;
  int fr = lane & 15, fk = (lane >> 4) * 8;

  f32x4 acc[4][4];
  const f32x4 vzero = {0.f, 0.f, 0.f, 0.f};
  for (int i = 0; i < 4; ++i)
    for (int j = 0; j < 4; ++j) acc[i][j] = vzero;

  for (int k0 = 0; k0 < D_; k0 += 64) {
    if (k0) __syncthreads();
    for (int i = 0; i < 4; ++i) {
      int base = ((i * 4 + wave) << 10);
      int ofs = base + lane * 16;
      int row = ofs >> 7;
      int scolb = (ofs & 127) ^ ((row & 7) << 4);
      gload_lds16(A + (size_t)(m0 + row) * D_ + k0 + (scolb >> 1), (char*)As + base);
      gload_lds16(Bt + (size_t)(n0 + row) * D_ + k0 + (scolb >> 1), (char*)Bs + base);
    }
    __syncthreads();
    for (int kh = 0; kh < 2; ++kh) {
      bf16x8 af[4], bfr[4];
      for (int mi = 0; mi < 4; ++mi) {
        int row = wr * 64 + mi * 16 + fr;
        af[mi] = *(const bf16x8*)((const char*)As + row * 128 +
                                  ((kh * 64 + fk * 2) ^ ((row & 7) << 4)));
      }
      for (int ni = 0; ni < 4; ++ni) {
        int row = wc * 64 + ni * 16 + fr;
        bfr[ni] = *(const bf16x8*)((const char*)Bs + row * 128 +
                                   ((kh * 64 + fk * 2) ^ ((row & 7) << 4)));
      }
      for (int mi = 0; mi < 4; ++mi)
        for (int ni = 0; ni < 4; ++ni)
          acc[mi][ni] =
              __builtin_amdgcn_mfma_f32_16x16x32_bf16(af[mi], bfr[ni], acc[mi][ni], 0, 0, 0);
    }
  }

  if (z == 2) {  // Vt [B][H][DH][S], key columns permuted within 64-key groups
    for (int mi = 0; mi < 4; ++mi) {
      int rowb = m0 + wr * 64 + mi * 16 + (lane >> 4) * 4;
      int bb2 = rowb >> 11, s0 = rowb & (S_ - 1);
      int l0 = s0 & 63;
      int p_local = ((l0 >> 5) & 1) * 32 + ((l0 >> 2) & 3) * 8 + ((l0 >> 4) & 1) * 4;
      int col2 = (s0 & ~63) | p_local;
      for (int ni = 0; ni < 4; ++ni) {
        int col = n0 + wc * 64 + ni * 16 + fr;
        int hh = col >> 6, dh = col & 63;
        float bv = bias[col];
        us4 pk;
        for (int r = 0; r < 4; ++r) pk[r] = f2bf(acc[mi][ni][r] + bv);
        *(us4*)(O + ((size_t)(bb2 * H_ + hh) * DH_ + dh) * S_ + col2) = pk;
      }
    }
  } else {       // Qh/Kh [B][H][S][DH]
    float scale = (z == 0) ? 0.125f : 1.0f;
    for (int mi = 0; mi < 4; ++mi) {
      int rowb = m0 + wr * 64 + mi * 16 + (lane >> 4) * 4;
      for (int ni = 0; ni < 4; ++ni) {
        int col = n0 + wc * 64 + ni * 16 + fr;
        int hh = col >> 6, dh = col & 63;
        float bv = bias[col];
        for (int r = 0; r < 4; ++r) {
          int row = rowb + r;
          int bb2 = row >> 11, s = row & (S_ - 1);
          O[((size_t)(bb2 * H_ + hh) * S_ + s) * DH_ + dh] =
              f2bf((acc[mi][ni][r] + bv) * scale);
        }
      }
    }
  }
}

// ---------------- output GEMM: BM=64 x BN=128, BK=64 (round-17 winner) ---------------
__global__ __launch_bounds__(256) void gemm_out(const u16* __restrict__ A,
                                                const u16* __restrict__ Bt,
                                                const float* __restrict__ bias,
                                                float* __restrict__ O) {
  __shared__ u16 As[64 * 64];    // 8 KB
  __shared__ u16 Bs[128 * 64];   // 16 KB
  int fid = blockIdx.x;
  int xcd = fid & 7, ii = fid >> 3;
  int grp = ii >> 3, yy = ii & 7;
  int gg = xcd * 8 + grp;
  int tid = threadIdx.x;
  int lane = tid & 63, wave = tid >> 6;
  int m0 = gg * 64, n0 = yy * 128;
  int fr = lane & 15, fk = (lane >> 4) * 8;

  f32x4 acc[4][2];
  const f32x4 vzero = {0.f, 0.f, 0.f, 0.f};
  for (int i = 0; i < 4; ++i)
    for (int j = 0; j < 2; ++j) acc[i][j] = vzero;

  for (int k0 = 0; k0 < D_; k0 += 64) {
    if (k0) __syncthreads();
    for (int i = 0; i < 2; ++i) {
      int base = ((i * 4 + wave) << 10);
      int ofs = base + lane * 16;
      int row = ofs >> 7;
      int scolb = (ofs & 127) ^ ((row & 7) << 4);
      gload_lds16(A + (size_t)(m0 + row) * D_ + k0 + (scolb >> 1), (char*)As + base);
    }
    for (int i = 0; i < 4; ++i) {
      int base = ((i * 4 + wave) << 10);
      int ofs = base + lane * 16;
      int row = ofs >> 7;
      int scolb = (ofs & 127) ^ ((row & 7) << 4);
      gload_lds16(Bt + (size_t)(n0 + row) * D_ + k0 + (scolb >> 1), (char*)Bs + base);
    }
    __syncthreads();
    for (int kh = 0; kh < 2; ++kh) {
      bf16x8 af[4], bfr[2];
      for (int mi = 0; mi < 4; ++mi) {
        int row = mi * 16 + fr;
        af[mi] = *(const bf16x8*)((const char*)As + row * 128 +
                                  ((kh * 64 + fk * 2) ^ ((row & 7) << 4)));
      }
      for (int ni = 0; ni < 2; ++ni) {
        int row = wave * 32 + ni * 16 + fr;
        bfr[ni] = *(const bf16x8*)((const char*)Bs + row * 128 +
                                   ((kh * 64 + fk * 2) ^ ((row & 7) << 4)));
      }
      for (int mi = 0; mi < 4; ++mi)
        for (int ni = 0; ni < 2; ++ni)
          acc[mi][ni] =
              __builtin_amdgcn_mfma_f32_16x16x32_bf16(af[mi], bfr[ni], acc[mi][ni], 0, 0, 0);
    }
  }

  for (int mi = 0; mi < 4; ++mi) {
    int rowb = m0 + mi * 16 + (lane >> 4) * 4;
    for (int ni = 0; ni < 2; ++ni) {
      int col = n0 + wave * 32 + ni * 16 + fr;
      float bv = bias[col];
      for (int r = 0; r < 4; ++r)
        O[(size_t)(rowb + r) * D_ + col] = acc[mi][ni][r] + bv;
    }
  }
}

// ---------------- flash attention v11: 32 q-rows/wave (halved LDS-read redundancy) ---
// 512 blocks x 256 threads; block = 128 q-rows (4 waves x 32). Each staged K/V tile
// feeds 2x more q -> ds_read_b128 count per q halves (the dominant modeled cost; the
// 12cy/b128 model postdicted round-14's delta). Grid: r=fid>>8, c=fid&255, e=c&7(XCD),
// g2=c>>3: h=e+8*(g2&1), b=(g2>>1)&1, p=g2>>2; stripe s128 = r? p : 15-p -> slot pairs
// (p,15-p) give constant 34 tiles/slot. Last TWO tiles masked (fully-masked tiles for
// low waves degrade safely to p=0). All v10 pieces preserved.
__global__ __launch_bounds__(256, 3) void attn_kernel(const u16* __restrict__ Qh,
                                                      const u16* __restrict__ Kh,
                                                      const u16* __restrict__ Vt,
                                                      const float* __restrict__ relb,
                                                      u16* __restrict__ attnout) {
  __shared__ u16 KVs[2][2][4096];  // [kind][buf][64x64 bf16] = 32 KB

  int fid = blockIdx.x;
  int r = fid >> 8, c = fid & 255;
  int e = c & 7, g2 = c >> 3;
  int h = e + 8 * (g2 & 1);
  int b = (g2 >> 1) & 1;
  int p = g2 >> 2;
  int s128 = r ? p : 15 - p;

  int w = threadIdx.x >> 6, lane = threadIdx.x & 63;
  int fr = lane & 15, g = lane >> 4;
  int q0w = s128 * 128 + w * 32;
  int qmeA = q0w + fr, qmeB = q0w + 16 + fr;
  int bh = b * H_ + h;
  int sx = (fr & 7) << 4;            // read-side XOR swizzle (bytes)

  int kind = w >> 1;
  int i0 = (w & 1) * 4;
  int srow_lo = lane >> 3;
  int scb = (lane & 7) * 16;

  const u16* Qb = Qh + ((size_t)bh * S_ + q0w) * DH_;
  bf16x8 qA0 = *(const bf16x8*)(Qb + fr * DH_ + 8 * g);
  bf16x8 qA1 = *(const bf16x8*)(Qb + fr * DH_ + 32 + 8 * g);
  bf16x8 qB0 = *(const bf16x8*)(Qb + (16 + fr) * DH_ + 8 * g);
  bf16x8 qB1 = *(const bf16x8*)(Qb + (16 + fr) * DH_ + 32 + 8 * g);

  const float* BqA = relb + (size_t)h * S_ * S_ + (size_t)qmeA * S_ + 4 * g;
  const float* BqB = relb + (size_t)h * S_ * S_ + (size_t)qmeB * S_ + 4 * g;
  const float LOG2E = 1.44269504f;

  int T = 2 * s128 + 2;

  auto STAGE = [&](int buf, int kb) {
    for (int i = 0; i < 4; ++i) {
      int ii = i0 + i;
      int row = ii * 8 + srow_lo;
      int cbs = scb ^ ((row & 7) << 4);
      const u16* src;
      if (kind == 0)
        src = Kh + ((size_t)bh * S_ + kb + row) * DH_ + (cbs >> 1);
      else
        src = Vt + ((size_t)bh * DH_ + row) * S_ + kb + (cbs >> 1);
      gload_lds16(src, &KVs[kind][buf][ii * 512]);
    }
  };

  f32x4 accA[4], accB[4];
  const f32x4 vzero = {0.f, 0.f, 0.f, 0.f};
  for (int f4 = 0; f4 < 4; ++f4) { accA[f4] = vzero; accB[f4] = vzero; }
  float mA = -1.0e4f, lA = 0.f, mB = -1.0e4f, lB = 0.f;

  STAGE(0, 0);
  f32x4 biA[4], biB[4], bnA[4], bnB[4];
  for (int cc = 0; cc < 4; ++cc) {
    biA[cc] = *(const f32x4*)(BqA + 16 * cc);
    biB[cc] = *(const f32x4*)(BqB + 16 * cc);
  }
  __syncthreads();

  for (int t = 0; t < T; ++t) {
    int kb = t * 64;
    int buf = t & 1;
    if (t + 1 < T) {
      STAGE(buf ^ 1, kb + 64);
      for (int cc = 0; cc < 4; ++cc) {
        bnA[cc] = *(const f32x4*)(BqA + kb + 64 + 16 * cc);
        bnB[cc] = *(const f32x4*)(BqB + kb + 64 + 16 * cc);
      }
    }

    const u16* Kt = &KVs[0][buf][0];
    const u16* Vl = &KVs[1][buf][0];

    // swapped QK^T, bias as C operand; K-frags shared across both q-groups
    f32x4 sA[4], sB[4];
    __builtin_amdgcn_s_setprio(1);
    for (int cc = 0; cc < 4; ++cc) {
      bf16x8 k0 = *(const bf16x8*)(Kt + (16 * cc + fr) * 64 + (((16 * g) ^ sx) >> 1));
      bf16x8 k1 = *(const bf16x8*)(Kt + (16 * cc + fr) * 64 + (((64 + 16 * g) ^ sx) >> 1));
      f32x4 zA = __builtin_amdgcn_mfma_f32_16x16x32_bf16(k0, qA0, biA[cc], 0, 0, 0);
      sA[cc] = __builtin_amdgcn_mfma_f32_16x16x32_bf16(k1, qA1, zA, 0, 0, 0);
      f32x4 zB = __builtin_amdgcn_mfma_f32_16x16x32_bf16(k0, qB0, biB[cc], 0, 0, 0);
      sB[cc] = __builtin_amdgcn_mfma_f32_16x16x32_bf16(k1, qB1, zB, 0, 0, 0);
    }
    __builtin_amdgcn_s_setprio(0);
    if (t >= 2 * s128) {  // only the last two tiles intersect the diagonal
      for (int cc = 0; cc < 4; ++cc)
        for (int rr = 0; rr < 4; ++rr) {
          int key = kb + 16 * cc + 4 * g + rr;
          sA[cc][rr] = (key <= qmeA) ? sA[cc][rr] : -1e30f;
          sB[cc][rr] = (key <= qmeB) ? sB[cc][rr] : -1e30f;
        }
    }
    // group A softmax
    {
      float pm = sA[0][0];
      for (int cc = 0; cc < 4; ++cc)
        for (int rr = 0; rr < 4; ++rr) pm = fmaxf(pm, sA[cc][rr]);
      pm = fmaxf(pm, __shfl_xor(pm, 16));
      pm = fmaxf(pm, __shfl_xor(pm, 32));
      if (!__all(pm - mA <= 8.0f)) {
        float mn = fmaxf(mA, pm);
        float corr = __expf(mA - mn);
        mA = mn;
        lA *= corr;
        float c0 = __shfl(corr, 4 * g + 0);
        float c1 = __shfl(corr, 4 * g + 1);
        float c2 = __shfl(corr, 4 * g + 2);
        float c3 = __shfl(corr, 4 * g + 3);
        for (int f4 = 0; f4 < 4; ++f4) {
          accA[f4][0] *= c0; accA[f4][1] *= c1; accA[f4][2] *= c2; accA[f4][3] *= c3;
        }
      }
      float nms = mA * -LOG2E, rs = 0.f;
      for (int cc = 0; cc < 4; ++cc)
        for (int rr = 0; rr < 4; ++rr) {
          sA[cc][rr] = fexp2(fmaf(sA[cc][rr], LOG2E, nms));
          rs += sA[cc][rr];
        }
      lA += rs;
    }
    // group B softmax
    {
      float pm = sB[0][0];
      for (int cc = 0; cc < 4; ++cc)
        for (int rr = 0; rr < 4; ++rr) pm = fmaxf(pm, sB[cc][rr]);
      pm = fmaxf(pm, __shfl_xor(pm, 16));
      pm = fmaxf(pm, __shfl_xor(pm, 32));
      if (!__all(pm - mB <= 8.0f)) {
        float mn = fmaxf(mB, pm);
        float corr = __expf(mB - mn);
        mB = mn;
        lB *= corr;
        float c0 = __shfl(corr, 4 * g + 0);
        float c1 = __shfl(corr, 4 * g + 1);
        float c2 = __shfl(corr, 4 * g + 2);
        float c3 = __shfl(corr, 4 * g + 3);
        for (int f4 = 0; f4 < 4; ++f4) {
          accB[f4][0] *= c0; accB[f4][1] *= c1; accB[f4][2] *= c2; accB[f4][3] *= c3;
        }
      }
      float nms = mB * -LOG2E, rs = 0.f;
      for (int cc = 0; cc < 4; ++cc)
        for (int rr = 0; rr < 4; ++rr) {
          sB[cc][rr] = fexp2(fmaf(sB[cc][rr], LOG2E, nms));
          rs += sB[cc][rr];
        }
      lB += rs;
    }
    union { unsigned int w4[4]; bf16x8 v; } ppA[2], ppB[2];
    for (int jj = 0; jj < 2; ++jj) {
      ppA[jj].w4[0] = cvtpk(sA[2 * jj][0], sA[2 * jj][1]);
      ppA[jj].w4[1] = cvtpk(sA[2 * jj][2], sA[2 * jj][3]);
      ppA[jj].w4[2] = cvtpk(sA[2 * jj + 1][0], sA[2 * jj + 1][1]);
      ppA[jj].w4[3] = cvtpk(sA[2 * jj + 1][2], sA[2 * jj + 1][3]);
      ppB[jj].w4[0] = cvtpk(sB[2 * jj][0], sB[2 * jj][1]);
      ppB[jj].w4[1] = cvtpk(sB[2 * jj][2], sB[2 * jj][3]);
      ppB[jj].w4[2] = cvtpk(sB[2 * jj + 1][0], sB[2 * jj + 1][1]);
      ppB[jj].w4[3] = cvtpk(sB[2 * jj + 1][2], sB[2 * jj + 1][3]);
    }
    // PV: each V b128 read once, feeds both q-groups
    __builtin_amdgcn_s_setprio(1);
    for (int f4 = 0; f4 < 4; ++f4) {
      for (int jj = 0; jj < 2; ++jj) {
        bf16x8 vv = *(const bf16x8*)(Vl + (f4 * 16 + fr) * 64 +
                                     (((jj * 64 + g * 16) ^ sx) >> 1));
        accA[f4] = __builtin_amdgcn_mfma_f32_16x16x32_bf16(ppA[jj].v, vv, accA[f4], 0, 0, 0);
        accB[f4] = __builtin_amdgcn_mfma_f32_16x16x32_bf16(ppB[jj].v, vv, accB[f4], 0, 0, 0);
      }
    }
    __builtin_amdgcn_s_setprio(0);
    for (int cc = 0; cc < 4; ++cc) { biA[cc] = bnA[cc]; biB[cc] = bnB[cc]; }
    __syncthreads();
  }

  // epilogue: reduce per-lane partial l across the 4 lanes sharing each q-row
  lA += __shfl_xor(lA, 16);
  lA += __shfl_xor(lA, 32);
  lB += __shfl_xor(lB, 16);
  lB += __shfl_xor(lB, 32);
  float ilA = 1.f / lA, ilB = 1.f / lB;
  for (int rr = 0; rr < 4; ++rr) {
    float ia = __shfl(ilA, 4 * g + rr);
    float ib = __shfl(ilB, 4 * g + rr);
    int qqA = q0w + 4 * g + rr;
    int qqB = q0w + 16 + 4 * g + rr;
    u16* obA = attnout + ((size_t)b * S_ + qqA) * D_ + h * 64;
    u16* obB = attnout + ((size_t)b * S_ + qqB) * D_ + h * 64;
    for (int f4 = 0; f4 < 4; ++f4) {
      obA[f4 * 16 + fr] = f2bf(accA[f4][rr] * ia);
      obB[f4 * 16 + fr] = f2bf(accB[f4][rr] * ib);
    }
  }
}

extern "C" void kernel_launch(void* const* d_in, const int* in_sizes, int n_in,
                              void* d_out, int out_size, void* d_ws, size_t ws_size,
                              hipStream_t stream) {
  const float* q = (const float*)d_in[0];
  const float* k = (const float*)d_in[1];
  const float* v = (const float*)d_in[2];
  const float* rb = (const float*)d_in[4];
  const float* Wq = (const float*)d_in[5];
  const float* bq = (const float*)d_in[6];
  const float* Wk = (const float*)d_in[7];
  const float* bk = (const float*)d_in[8];
  const float* Wv = (const float*)d_in[9];
  const float* bv = (const float*)d_in[10];
  const float* Wo = (const float*)d_in[11];
  const float* bo = (const float*)d_in[12];
  float* out = (float*)d_out;

  char* ws = (char*)d_ws;
  const size_t SZ = (size_t)M_ * D_ * 2;
  u16* Xq = (u16*)(ws);
  u16* Xk = (u16*)(ws + SZ);
  u16* Xv = (u16*)(ws + 2 * SZ);
  u16* Qh = (u16*)(ws + 3 * SZ);
  u16* Kh = (u16*)(ws + 4 * SZ);
  u16* Vt = (u16*)(ws + 5 * SZ);
  u16* Wt = (u16*)(ws + 6 * SZ);
  u16* Xb = Xq;

  wprep_kernel<<<dim3(32, 32, 7), dim3(32, 8), 0, stream>>>(Wq, Wk, Wv, Wo, Wt,
                                                            q, k, v, Xq, Xk, Xv);

  gemm_qkv<<<dim3(768), 256, 0, stream>>>(Xq, Xk, Xv, Wt, bq, bk, bv, Qh, Kh, Vt);

  attn_kernel<<<dim3(512), 256, 0, stream>>>(Qh, Kh, Vt, rb, Xb);

  gemm_out<<<dim3(512), 256, 0, stream>>>(Xb, Wt + 3 * (size_t)D_ * D_, bo, out);
}

// Round 19
// 128.091 us; speedup vs baseline: 1.1116x; 1.1116x over previous
//
#include <hip/hip_runtime.h>

typedef unsigned short u16;
typedef __attribute__((ext_vector_type(8))) short bf16x8;
typedef __attribute__((ext_vector_type(4))) float f32x4;
typedef __attribute__((ext_vector_type(4))) unsigned short us4;

#define B_ 2
#define S_ 2048
#define D_ 1024
#define H_ 16
#define DH_ 64
#define M_ 4096 /* B*S */

__device__ __forceinline__ u16 f2bf(float f) {
  unsigned int u = __builtin_bit_cast(unsigned int, f);
  u += 0x7FFFu + ((u >> 16) & 1u);   // RNE
  return (u16)(u >> 16);
}

__device__ __forceinline__ unsigned int cvtpk(float lo, float hi) {
  unsigned int r;
  asm("v_cvt_pk_bf16_f32 %0, %1, %2" : "=v"(r) : "v"(lo), "v"(hi));
  return r;
}

__device__ __forceinline__ float fexp2(float x) {  // v_exp_f32 IS exp2
  float r;
  asm("v_exp_f32 %0, %1" : "=v"(r) : "v"(x));
  return r;
}

__device__ __forceinline__ void gload_lds16(const void* g, void* l) {
  __builtin_amdgcn_global_load_lds(
      (__attribute__((address_space(1))) void*)(g),
      (__attribute__((address_space(3))) void*)(l),
      16, 0, 0);
}

// ---------------- prep: z<4 -> W[z] transpose+cvt; z>=4 -> q/k/v fp32->bf16 ----------
__global__ __launch_bounds__(256) void wprep_kernel(const float* __restrict__ W0,
                                                    const float* __restrict__ W1,
                                                    const float* __restrict__ W2,
                                                    const float* __restrict__ W3,
                                                    u16* __restrict__ Wt,
                                                    const float* __restrict__ qin,
                                                    const float* __restrict__ kin,
                                                    const float* __restrict__ vin,
                                                    u16* __restrict__ Xq,
                                                    u16* __restrict__ Xk,
                                                    u16* __restrict__ Xv) {
  int z = blockIdx.z;
  if (z < 4) {
    __shared__ float tile[32][33];
    const float* W = (z == 0) ? W0 : (z == 1) ? W1 : (z == 2) ? W2 : W3;
    u16* out = Wt + (size_t)z * D_ * D_;
    int tx = threadIdx.x, ty = threadIdx.y;
    int x = blockIdx.x * 32 + tx;
    for (int j = 0; j < 32; j += 8)
      tile[ty + j][tx] = W[(size_t)(blockIdx.y * 32 + ty + j) * D_ + x];
    __syncthreads();
    int x2 = blockIdx.y * 32 + tx;
    for (int j = 0; j < 32; j += 8)
      out[(size_t)(blockIdx.x * 32 + ty + j) * D_ + x2] = f2bf(tile[tx][ty + j]);
  } else {
    int zz = z - 4;
    const float* src = (zz == 0) ? qin : (zz == 1) ? kin : vin;
    u16* dst = (zz == 0) ? Xq : (zz == 1) ? Xk : Xv;
    int bid = blockIdx.y * 32 + blockIdx.x;
    int t = threadIdx.y * 32 + threadIdx.x;
    const float4* s4 = (const float4*)src;
    for (int i = 0; i < 4; ++i) {
      int idx = bid * 1024 + i * 256 + t;
      float4 v4 = s4[idx];
      us4 o;
      o[0] = f2bf(v4.x); o[1] = f2bf(v4.y); o[2] = f2bf(v4.z); o[3] = f2bf(v4.w);
      ((us4*)dst)[idx] = o;
    }
  }
}

// ---------------- QKV GEMM: BK=64, XOR-swizzled LDS tiles (round-17 winner) ----------
__global__ __launch_bounds__(256) void gemm_qkv(const u16* __restrict__ Xq,
                                                const u16* __restrict__ Xk,
                                                const u16* __restrict__ Xv,
                                                const u16* __restrict__ Wt,
                                                const float* __restrict__ bq,
                                                const float* __restrict__ bk,
                                                const float* __restrict__ bv,
                                                u16* __restrict__ Qh,
                                                u16* __restrict__ Kh,
                                                u16* __restrict__ Vt) {
  __shared__ u16 As[128 * 64];   // 16 KB
  __shared__ u16 Bs[128 * 64];   // 16 KB
  int fid = blockIdx.x;
  int xcd = fid & 7, ii = fid >> 3;
  int grp = ii >> 3, yy = ii & 7;
  int gg = xcd * 12 + grp;
  int z = gg >> 5;
  int xx = gg & 31;
  const u16* A = (z == 0) ? Xq : (z == 1) ? Xk : Xv;
  const u16* Bt = Wt + (size_t)z * D_ * D_;
  const float* bias = (z == 0) ? bq : (z == 1) ? bk : bv;
  u16* O = (z == 0) ? Qh : (z == 1) ? Kh : Vt;

  int tid = threadIdx.x;
  int lane = tid & 63, wave = tid >> 6;
  int m0 = xx * 128, n0 = yy * 128;
  int wr = wave >> 1, wc = wave & 1;
  int fr = lane & 15, fk = (lane >> 4) * 8;

  f32x4 acc[4][4];
  const f32x4 vzero = {0.f, 0.f, 0.f, 0.f};
  for (int i = 0; i < 4; ++i)
    for (int j = 0; j < 4; ++j) acc[i][j] = vzero;

  for (int k0 = 0; k0 < D_; k0 += 64) {
    if (k0) __syncthreads();
    for (int i = 0; i < 4; ++i) {
      int base = ((i * 4 + wave) << 10);
      int ofs = base + lane * 16;
      int row = ofs >> 7;
      int scolb = (ofs & 127) ^ ((row & 7) << 4);
      gload_lds16(A + (size_t)(m0 + row) * D_ + k0 + (scolb >> 1), (char*)As + base);
      gload_lds16(Bt + (size_t)(n0 + row) * D_ + k0 + (scolb >> 1), (char*)Bs + base);
    }
    __syncthreads();
    for (int kh = 0; kh < 2; ++kh) {
      bf16x8 af[4], bfr[4];
      for (int mi = 0; mi < 4; ++mi) {
        int row = wr * 64 + mi * 16 + fr;
        af[mi] = *(const bf16x8*)((const char*)As + row * 128 +
                                  ((kh * 64 + fk * 2) ^ ((row & 7) << 4)));
      }
      for (int ni = 0; ni < 4; ++ni) {
        int row = wc * 64 + ni * 16 + fr;
        bfr[ni] = *(const bf16x8*)((const char*)Bs + row * 128 +
                                   ((kh * 64 + fk * 2) ^ ((row & 7) << 4)));
      }
      for (int mi = 0; mi < 4; ++mi)
        for (int ni = 0; ni < 4; ++ni)
          acc[mi][ni] =
              __builtin_amdgcn_mfma_f32_16x16x32_bf16(af[mi], bfr[ni], acc[mi][ni], 0, 0, 0);
    }
  }

  if (z == 2) {  // Vt [B][H][DH][S], key columns permuted within 64-key groups
    for (int mi = 0; mi < 4; ++mi) {
      int rowb = m0 + wr * 64 + mi * 16 + (lane >> 4) * 4;
      int bb2 = rowb >> 11, s0 = rowb & (S_ - 1);
      int l0 = s0 & 63;
      int p_local = ((l0 >> 5) & 1) * 32 + ((l0 >> 2) & 3) * 8 + ((l0 >> 4) & 1) * 4;
      int col2 = (s0 & ~63) | p_local;
      for (int ni = 0; ni < 4; ++ni) {
        int col = n0 + wc * 64 + ni * 16 + fr;
        int hh = col >> 6, dh = col & 63;
        float bv = bias[col];
        us4 pk;
        for (int r = 0; r < 4; ++r) pk[r] = f2bf(acc[mi][ni][r] + bv);
        *(us4*)(O + ((size_t)(bb2 * H_ + hh) * DH_ + dh) * S_ + col2) = pk;
      }
    }
  } else {       // Qh/Kh [B][H][S][DH]
    float scale = (z == 0) ? 0.125f : 1.0f;
    for (int mi = 0; mi < 4; ++mi) {
      int rowb = m0 + wr * 64 + mi * 16 + (lane >> 4) * 4;
      for (int ni = 0; ni < 4; ++ni) {
        int col = n0 + wc * 64 + ni * 16 + fr;
        int hh = col >> 6, dh = col & 63;
        float bv = bias[col];
        for (int r = 0; r < 4; ++r) {
          int row = rowb + r;
          int bb2 = row >> 11, s = row & (S_ - 1);
          O[((size_t)(bb2 * H_ + hh) * S_ + s) * DH_ + dh] =
              f2bf((acc[mi][ni][r] + bv) * scale);
        }
      }
    }
  }
}

// ---------------- output GEMM: BM=64 x BN=128, BK=64 (round-17 winner) ---------------
__global__ __launch_bounds__(256) void gemm_out(const u16* __restrict__ A,
                                                const u16* __restrict__ Bt,
                                                const float* __restrict__ bias,
                                                float* __restrict__ O) {
  __shared__ u16 As[64 * 64];    // 8 KB
  __shared__ u16 Bs[128 * 64];   // 16 KB
  int fid = blockIdx.x;
  int xcd = fid & 7, ii = fid >> 3;
  int grp = ii >> 3, yy = ii & 7;
  int gg = xcd * 8 + grp;
  int tid = threadIdx.x;
  int lane = tid & 63, wave = tid >> 6;
  int m0 = gg * 64, n0 = yy * 128;
  int fr = lane & 15, fk = (lane >> 4) * 8;

  f32x4 acc[4][2];
  const f32x4 vzero = {0.f, 0.f, 0.f, 0.f};
  for (int i = 0; i < 4; ++i)
    for (int j = 0; j < 2; ++j) acc[i][j] = vzero;

  for (int k0 = 0; k0 < D_; k0 += 64) {
    if (k0) __syncthreads();
    for (int i = 0; i < 2; ++i) {
      int base = ((i * 4 + wave) << 10);
      int ofs = base + lane * 16;
      int row = ofs >> 7;
      int scolb = (ofs & 127) ^ ((row & 7) << 4);
      gload_lds16(A + (size_t)(m0 + row) * D_ + k0 + (scolb >> 1), (char*)As + base);
    }
    for (int i = 0; i < 4; ++i) {
      int base = ((i * 4 + wave) << 10);
      int ofs = base + lane * 16;
      int row = ofs >> 7;
      int scolb = (ofs & 127) ^ ((row & 7) << 4);
      gload_lds16(Bt + (size_t)(n0 + row) * D_ + k0 + (scolb >> 1), (char*)Bs + base);
    }
    __syncthreads();
    for (int kh = 0; kh < 2; ++kh) {
      bf16x8 af[4], bfr[2];
      for (int mi = 0; mi < 4; ++mi) {
        int row = mi * 16 + fr;
        af[mi] = *(const bf16x8*)((const char*)As + row * 128 +
                                  ((kh * 64 + fk * 2) ^ ((row & 7) << 4)));
      }
      for (int ni = 0; ni < 2; ++ni) {
        int row = wave * 32 + ni * 16 + fr;
        bfr[ni] = *(const bf16x8*)((const char*)Bs + row * 128 +
                                   ((kh * 64 + fk * 2) ^ ((row & 7) << 4)));
      }
      for (int mi = 0; mi < 4; ++mi)
        for (int ni = 0; ni < 2; ++ni)
          acc[mi][ni] =
              __builtin_amdgcn_mfma_f32_16x16x32_bf16(af[mi], bfr[ni], acc[mi][ni], 0, 0, 0);
    }
  }

  for (int mi = 0; mi < 4; ++mi) {
    int rowb = m0 + mi * 16 + (lane >> 4) * 4;
    for (int ni = 0; ni < 2; ++ni) {
      int col = n0 + wave * 32 + ni * 16 + fr;
      float bv = bias[col];
      for (int r = 0; r < 4; ++r)
        O[(size_t)(rowb + r) * D_ + col] = acc[mi][ni][r] + bv;
    }
  }
}

// ---------------- flash attention v10 (round-17 anchor) ----------------
__global__ __launch_bounds__(256, 4) void attn_kernel(const u16* __restrict__ Qh,
                                                      const u16* __restrict__ Kh,
                                                      const u16* __restrict__ Vt,
                                                      const float* __restrict__ relb,
                                                      u16* __restrict__ attnout) {
  __shared__ u16 KVs[2][2][4096];  // [kind][buf][64x64 bf16] = 32 KB

  int fid = blockIdx.x;
  int rr = fid >> 8, c = fid & 255;
  int j = c >> 3, e = c & 7;
  int s = (rr & 1) ? j : 31 - j;
  int h = (rr & 1) ? e + 8 : e;
  int b = rr >> 1;

  int w = threadIdx.x >> 6, lane = threadIdx.x & 63;
  int fr = lane & 15, g = lane >> 4;
  int q0w = s * 64 + w * 16;
  int qme = q0w + fr;
  int bh = b * H_ + h;
  int sx = (fr & 7) << 4;            // read-side XOR swizzle (bytes)

  int kind = w >> 1;
  int i0 = (w & 1) * 4;
  int srow_lo = lane >> 3;
  int scb = (lane & 7) * 16;

  const u16* Qb = Qh + ((size_t)bh * S_ + q0w) * DH_;
  bf16x8 qf0 = *(const bf16x8*)(Qb + fr * DH_ + 8 * g);
  bf16x8 qf1 = *(const bf16x8*)(Qb + fr * DH_ + 32 + 8 * g);

  const float* Bq = relb + (size_t)h * S_ * S_ + (size_t)qme * S_ + 4 * g;
  const float LOG2E = 1.44269504f;

  int T = s + 1;

  auto STAGE = [&](int buf, int kb) {
    for (int i = 0; i < 4; ++i) {
      int ii = i0 + i;
      int row = ii * 8 + srow_lo;
      int cbs = scb ^ ((row & 7) << 4);
      const u16* src;
      if (kind == 0)
        src = Kh + ((size_t)bh * S_ + kb + row) * DH_ + (cbs >> 1);
      else
        src = Vt + ((size_t)bh * DH_ + row) * S_ + kb + (cbs >> 1);
      gload_lds16(src, &KVs[kind][buf][ii * 512]);
    }
  };

  f32x4 acc[4];
  const f32x4 vzero = {0.f, 0.f, 0.f, 0.f};
  for (int f4 = 0; f4 < 4; ++f4) acc[f4] = vzero;
  float m = -1.0e4f, l = 0.f;   // per-lane partial l; first tile always rescales

  STAGE(0, 0);
  f32x4 bi[4], bn[4];
  for (int cc = 0; cc < 4; ++cc) bi[cc] = *(const f32x4*)(Bq + 16 * cc);
  __syncthreads();

  for (int t = 0; t < T; ++t) {
    int kb = t * 64;
    int buf = t & 1;
    bool diag = (t == T - 1);
    if (!diag) {
      STAGE(buf ^ 1, kb + 64);
      for (int cc = 0; cc < 4; ++cc) bn[cc] = *(const f32x4*)(Bq + kb + 64 + 16 * cc);
    }

    const u16* Kt = &KVs[0][buf][0];
    const u16* Vl = &KVs[1][buf][0];

    // swapped QK^T with bias as the C operand
    f32x4 sc[4];
    __builtin_amdgcn_s_setprio(1);
    for (int cc = 0; cc < 4; ++cc) {
      bf16x8 k0 = *(const bf16x8*)(Kt + (16 * cc + fr) * 64 + (((16 * g) ^ sx) >> 1));
      bf16x8 k1 = *(const bf16x8*)(Kt + (16 * cc + fr) * 64 + (((64 + 16 * g) ^ sx) >> 1));
      f32x4 z = __builtin_amdgcn_mfma_f32_16x16x32_bf16(k0, qf0, bi[cc], 0, 0, 0);
      z = __builtin_amdgcn_mfma_f32_16x16x32_bf16(k1, qf1, z, 0, 0, 0);
      sc[cc] = z;
    }
    __builtin_amdgcn_s_setprio(0);
    if (diag) {  // only the diagonal tile needs causal masking (bias already in)
      for (int cc = 0; cc < 4; ++cc)
        for (int r = 0; r < 4; ++r) {
          int key = kb + 16 * cc + 4 * g + r;
          sc[cc][r] = (key <= qme) ? sc[cc][r] : -1e30f;
        }
    }
    float pm = sc[0][0];
    for (int cc = 0; cc < 4; ++cc)
      for (int r = 0; r < 4; ++r) pm = fmaxf(pm, sc[cc][r]);
    pm = fmaxf(pm, __shfl_xor(pm, 16));
    pm = fmaxf(pm, __shfl_xor(pm, 32));
    if (!__all(pm - m <= 8.0f)) {
      float mn = fmaxf(m, pm);
      float corr = __expf(m - mn);
      m = mn;
      l *= corr;
      float c0 = __shfl(corr, 4 * g + 0);
      float c1 = __shfl(corr, 4 * g + 1);
      float c2 = __shfl(corr, 4 * g + 2);
      float c3 = __shfl(corr, 4 * g + 3);
      for (int f4 = 0; f4 < 4; ++f4) {
        acc[f4][0] *= c0; acc[f4][1] *= c1; acc[f4][2] *= c2; acc[f4][3] *= c3;
      }
    }
    float nms = m * -LOG2E;
    float rs = 0.f;
    for (int cc = 0; cc < 4; ++cc)
      for (int r = 0; r < 4; ++r) {
        sc[cc][r] = fexp2(fmaf(sc[cc][r], LOG2E, nms));
        rs += sc[cc][r];
      }
    l += rs;
    union { unsigned int w4[4]; bf16x8 v; } pp[2];
    for (int jj = 0; jj < 2; ++jj) {
      pp[jj].w4[0] = cvtpk(sc[2 * jj][0], sc[2 * jj][1]);
      pp[jj].w4[1] = cvtpk(sc[2 * jj][2], sc[2 * jj][3]);
      pp[jj].w4[2] = cvtpk(sc[2 * jj + 1][0], sc[2 * jj + 1][1]);
      pp[jj].w4[3] = cvtpk(sc[2 * jj + 1][2], sc[2 * jj + 1][3]);
    }
    // PV: V pre-permuted -> one b128 per (f4, jj), conflict-free
    __builtin_amdgcn_s_setprio(1);
    for (int f4 = 0; f4 < 4; ++f4) {
      for (int jj = 0; jj < 2; ++jj) {
        bf16x8 vv = *(const bf16x8*)(Vl + (f4 * 16 + fr) * 64 +
                                     (((jj * 64 + g * 16) ^ sx) >> 1));
        acc[f4] = __builtin_amdgcn_mfma_f32_16x16x32_bf16(pp[jj].v, vv, acc[f4], 0, 0, 0);
      }
    }
    __builtin_amdgcn_s_setprio(0);
    for (int cc = 0; cc < 4; ++cc) bi[cc] = bn[cc];
    __syncthreads();
  }

  // epilogue: reduce per-lane partial l across the 4 lanes sharing each q-row
  l += __shfl_xor(l, 16);
  l += __shfl_xor(l, 32);
  float il = 1.f / l;
  for (int r = 0; r < 4; ++r) {
    float ilr = __shfl(il, 4 * g + r);
    int qq = q0w + 4 * g + r;
    u16* ob = attnout + ((size_t)b * S_ + qq) * D_ + h * 64;
    for (int f4 = 0; f4 < 4; ++f4) ob[f4 * 16 + fr] = f2bf(acc[f4][r] * ilr);
  }
}

extern "C" void kernel_launch(void* const* d_in, const int* in_sizes, int n_in,
                              void* d_out, int out_size, void* d_ws, size_t ws_size,
                              hipStream_t stream) {
  const float* q = (const float*)d_in[0];
  const float* k = (const float*)d_in[1];
  const float* v = (const float*)d_in[2];
  const float* rb = (const float*)d_in[4];
  const float* Wq = (const float*)d_in[5];
  const float* bq = (const float*)d_in[6];
  const float* Wk = (const float*)d_in[7];
  const float* bk = (const float*)d_in[8];
  const float* Wv = (const float*)d_in[9];
  const float* bv = (const float*)d_in[10];
  const float* Wo = (const float*)d_in[11];
  const float* bo = (const float*)d_in[12];
  float* out = (float*)d_out;

  char* ws = (char*)d_ws;
  const size_t SZ = (size_t)M_ * D_ * 2;
  u16* Xq = (u16*)(ws);
  u16* Xk = (u16*)(ws + SZ);
  u16* Xv = (u16*)(ws + 2 * SZ);
  u16* Qh = (u16*)(ws + 3 * SZ);
  u16* Kh = (u16*)(ws + 4 * SZ);
  u16* Vt = (u16*)(ws + 5 * SZ);
  u16* Wt = (u16*)(ws + 6 * SZ);
  u16* Xb = Xq;

  wprep_kernel<<<dim3(32, 32, 7), dim3(32, 8), 0, stream>>>(Wq, Wk, Wv, Wo, Wt,
                                                            q, k, v, Xq, Xk, Xv);

  gemm_qkv<<<dim3(768), 256, 0, stream>>>(Xq, Xk, Xv, Wt, bq, bk, bv, Qh, Kh, Vt);

  attn_kernel<<<dim3(1024), 256, 0, stream>>>(Qh, Kh, Vt, rb, Xb);

  gemm_out<<<dim3(512), 256, 0, stream>>>(Xb, Wt + 3 * (size_t)D_ * D_, bo, out);
}